// Round 1
// 219.753 us; speedup vs baseline: 1.0147x; 1.0147x over previous
//
#include <hip/hip_runtime.h>
#include <math.h>

// NuclearLoss: cls_score (8,19,512,512) fp32 -> scalar fp32.
// loss = -(1/B) * sum over patches,channels of sqrt( sum_pixels softmax(x)[c]^2 )
// B = 8 * 32 * 32 = 8192 patches of 16x16.

#define NIMG 8
#define CCH  19
#define HH   512
#define WW   512
#define CHST (HH * WW)          // channel stride in floats (262144)

// Block: 256 threads cover a 16-row x 64-col region = 4 full 16x16 patches.
// Each thread owns ONE float4 (4 consecutive cols of one row):
//   row = tid>>4 (16 rows), col-group cg = tid&15 (16 groups x 4 cols).
// Wave w holds rows 4w..4w+3; per channel each wave issues one
// global_load_dwordx4 (64 lanes x 16B = 1KB, four dense 256B row segments).
// All 19 channel loads are issued before any use -> 19 KB in flight per wave.
__global__ __launch_bounds__(256, 4) void nuclear_loss_kernel(
    const float* __restrict__ in, float* __restrict__ out) {
    __shared__ float psum[4 * CCH];  // per-(local patch, channel) diag sums

    const int tid  = threadIdx.x;
    const int b    = blockIdx.x;
    const int n    = b >> 8;       // 256 blocks per image
    const int rem  = b & 255;
    const int prow = rem >> 3;     // patch row 0..31
    const int creg = rem & 7;      // 64-col region 0..7
    const int cg   = tid & 15;     // col-group (4 cols each)
    const int row  = (prow << 4) + (tid >> 4);
    const int col  = (creg << 6) + (cg << 2);

    for (int i = tid; i < 4 * CCH; i += 256) psum[i] = 0.0f;
    __syncthreads();

    const float* bp = in + (size_t)n * (size_t)(CCH * CHST)
                         + (size_t)row * WW + col;

    // 19 x dwordx4, issued back-to-back (no dependent use in between).
    float4 v[CCH];
#pragma unroll
    for (int c = 0; c < CCH; ++c)
        v[c] = *reinterpret_cast<const float4*>(bp + (size_t)c * CHST);

    // Softmax denominators for the thread's 4 pixels.
    // No max-subtraction: inputs ~N(0,1), exp stays well inside fp32.
    float sx = 0.f, sy = 0.f, sz = 0.f, sw = 0.f;
#pragma unroll
    for (int c = 0; c < CCH; ++c) {
        v[c].x = __expf(v[c].x); sx += v[c].x;
        v[c].y = __expf(v[c].y); sy += v[c].y;
        v[c].z = __expf(v[c].z); sz += v[c].z;
        v[c].w = __expf(v[c].w); sw += v[c].w;
    }
    // v_rcp_f32 (~1 ulp) instead of IEEE divide: loss-level error ~1e-5.
    const float ix = __builtin_amdgcn_rcpf(sx);
    const float iy = __builtin_amdgcn_rcpf(sy);
    const float iz = __builtin_amdgcn_rcpf(sz);
    const float iw = __builtin_amdgcn_rcpf(sw);

    const int  lane   = tid & 63;
    const bool lead   = (lane < 16) && ((lane & 3) == 0);
    const int  plocal = cg >> 2;   // which of the 4 patches

    // Per channel: prob^2 summed over this thread's 4 pixels, then reduce
    // rows within the wave (lanes ^16, ^32) and the patch's 4 col-groups.
    // Folding the reduce into this loop keeps the per-channel partial a
    // scalar (no part[19] array -> lower VGPR pressure).
#pragma unroll
    for (int c = 0; c < CCH; ++c) {
        const float tx = v[c].x * ix;
        const float ty = v[c].y * iy;
        const float tz = v[c].z * iz;
        const float tw = v[c].w * iw;
        float x = tx * tx;
        x = fmaf(ty, ty, x);
        x = fmaf(tz, tz, x);
        x = fmaf(tw, tw, x);
        x += __shfl_xor(x, 16, 64);   // rows 4w ^ 4w+1 pairs... (row bits are lane[5:4])
        x += __shfl_xor(x, 32, 64);
        x += __shfl_down(x, 2, 4);    // 4 col-groups of the patch
        x += __shfl_down(x, 1, 4);
        if (lead) atomicAdd(&psum[plocal * CCH + c], x);  // 4 leaders/wave
    }
    __syncthreads();

    // Wave 0: sqrt the 76 diag entries, sum, single global atomic per block.
    if (tid < 64) {
        float v2 = (tid < 4 * CCH) ? sqrtf(psum[tid]) : 0.0f;
        if (tid + 64 < 4 * CCH) v2 += sqrtf(psum[tid + 64]);
        v2 += __shfl_down(v2, 32, 64);
        v2 += __shfl_down(v2, 16, 64);
        v2 += __shfl_down(v2, 8, 64);
        v2 += __shfl_down(v2, 4, 64);
        v2 += __shfl_down(v2, 2, 64);
        v2 += __shfl_down(v2, 1, 64);
        if (tid == 0) atomicAdd(out, v2 * (-1.0f / 8192.0f));
    }
}

extern "C" void kernel_launch(void* const* d_in, const int* in_sizes, int n_in,
                              void* d_out, int out_size, void* d_ws, size_t ws_size,
                              hipStream_t stream) {
    const float* in = (const float*)d_in[0];
    float* out = (float*)d_out;
    // d_out is poisoned to 0xAA before every call; zero it (capturable memset node).
    hipMemsetAsync(out, 0, sizeof(float), stream);
    // 8 images * 32 patch-rows * 8 col-regions = 2048 blocks
    nuclear_loss_kernel<<<2048, 256, 0, stream>>>(in, out);
}